// Round 8
// baseline (519.930 us; speedup 1.0000x reference)
//
#include <hip/hip_runtime.h>
#include <math.h>

#define B_SZ 8192
#define D_DIM 512
#define C_DIM 1000
#define C_PAD 1024
#define K_EXP 8
#define TEMP_INV 5.0f
#define EPS_N 1e-8f

typedef __attribute__((ext_vector_type(8))) short frag_ab;
typedef __attribute__((ext_vector_type(16))) float f32x16;

__device__ __forceinline__ short f2bf(float f) {
    unsigned u = __builtin_bit_cast(unsigned, f);
    unsigned r = (u + 0x7fffu + ((u >> 16) & 1u)) >> 16;
    return (short)r;
}
__device__ __forceinline__ float bf2f(short s) {
    unsigned u = ((unsigned)(unsigned short)s) << 16;
    return __builtin_bit_cast(float, u);
}
// 2-plane split: v ~= s0 + s1, |residual| ~ 2^-18 |v|
__device__ __forceinline__ void split2(float v, short& s0, short& s1) {
    s0 = f2bf(v);
    s1 = f2bf(v - bf2f(s0));
}

// async global->LDS, 16B per lane (LDS dest wave-contiguous: base + lane*16)
__device__ __forceinline__ void gl_lds16(const short* g, short* l) {
    __builtin_amdgcn_global_load_lds(
        (const __attribute__((address_space(1))) unsigned int*)(const void*)g,
        (__attribute__((address_space(3))) unsigned int*)(void*)l,
        16, 0, 0);
}

// ---------------- one-time prep: transpose + 2-way bf16 split ----------------
__global__ __launch_bounds__(256) void prep_z(const float* __restrict__ z,
                                              short* __restrict__ p0, short* __restrict__ p1) {
    int idx = blockIdx.x * 256 + threadIdx.x;
    float v = z[idx];
    short a, b; split2(v, a, b);
    p0[idx] = a; p1[idx] = b;
}

// W1 [K][d][e] -> planes [K][e][d], LDS 32x32 tile transpose
__global__ __launch_bounds__(256) void prep_w1t(const float* __restrict__ W1,
                                                short* __restrict__ p0, short* __restrict__ p1) {
    __shared__ float t[32][33];
    const int k = blockIdx.z;
    const int d0 = blockIdx.x * 32;
    const int e0 = blockIdx.y * 32;
    const int tx = threadIdx.x & 31, ty = threadIdx.x >> 5;
    const float* src = W1 + ((size_t)k << 18);
#pragma unroll
    for (int r = 0; r < 4; r++) {
        int d = d0 + ty + 8 * r;
        t[ty + 8 * r][tx] = src[(size_t)d * 512 + e0 + tx];
    }
    __syncthreads();
#pragma unroll
    for (int r = 0; r < 4; r++) {
        int e = e0 + ty + 8 * r;
        int d = d0 + tx;
        float v = t[tx][ty + 8 * r];
        short a, b; split2(v, a, b);
        size_t o = ((size_t)k << 18) + (size_t)e * 512 + d;
        p0[o] = a; p1[o] = b;
    }
}

// W2 [K][e][c] -> planes [K][c_pad][e] (zero rows c>=1000), 32x32 tile transpose
__global__ __launch_bounds__(256) void prep_w2t(const float* __restrict__ W2,
                                                short* __restrict__ p0, short* __restrict__ p1) {
    __shared__ float t[32][33];
    const int k = blockIdx.z;
    const int e0 = blockIdx.x * 32;
    const int c0 = blockIdx.y * 32;
    const int tx = threadIdx.x & 31, ty = threadIdx.x >> 5;
    const float* src = W2 + (size_t)k * (D_DIM * C_DIM);
#pragma unroll
    for (int r = 0; r < 4; r++) {
        int e = e0 + ty + 8 * r;
        int c = c0 + tx;
        t[ty + 8 * r][tx] = (c < C_DIM) ? src[(size_t)e * C_DIM + c] : 0.f;
    }
    __syncthreads();
#pragma unroll
    for (int r = 0; r < 4; r++) {
        int c = c0 + ty + 8 * r;
        int e = e0 + tx;
        float v = t[tx][ty + 8 * r];
        short a, b; split2(v, a, b);
        size_t o = (size_t)k * (C_PAD * D_DIM) + (size_t)c * 512 + e;
        p0[o] = a; p1[o] = b;
    }
}

// ---------------- split-bf16 MFMA GEMM: 256x256 block, 32x32x16 MFMA ----------------
// R8: R3's staging/schedule verbatim; inner tile swapped to mfma_f32_32x32x16_bf16
// (2495 TF ceiling vs 2176 for 16x16x32; half the MFMA instruction count).
// Wave tile 128x64 = 4x2 blocks of 32x32. Operand layout: lane = row(col)+32*k_half,
// 8 contiguous k per lane -> same chunk-of-8 swizzled LDS reads as before.
// C/D layout (verified): col=lane&31, row=(reg&3)+8*(reg>>2)+4*(lane>>5).
__global__ __launch_bounds__(512, 2) void gemm_split(
    const short* __restrict__ A0, const short* __restrict__ A1, long long aBatch,
    const short* __restrict__ B0, const short* __restrict__ B1, long long bBatch,
    const float* __restrict__ bias, int biasBatch,
    float* __restrict__ Cf, long long cBatch, int ldc, int Nout,
    short* __restrict__ H0, short* __restrict__ H1, long long hBatch,
    int mt, int nt, int mode)
{
    const int lin = blockIdx.x;
    const int k = lin & 7;                  // expert ↔ XCD affinity
    const int rem = lin >> 3;
    const int gm = (mt >= 2) ? 2 : 1;       // m-window (512-row L2 window)
    const int win = rem / (gm * nt);
    const int local = rem % (gm * nt);
    const int m0 = (win * gm + local / nt) * 256;
    const int n0 = (local % nt) * 256;

    const int tid = threadIdx.x;
    const int lane = tid & 63;
    const int wv = tid >> 6;                // 0..7
    const int wm = (wv & 1) * 128;          // wave tile: 128 rows x 64 cols
    const int wn = (wv >> 1) * 64;

    // A: 2 bufs x 2 planes x 256x32 = 32768 shorts; B same; total 128 KiB
    __shared__ short lds[65536];
    short* ldsA = lds;
    short* ldsB = lds + 32768;

    const short* aP0 = A0 + (size_t)k * aBatch + (size_t)m0 * 512;
    const short* aP1 = A1 + (size_t)k * aBatch + (size_t)m0 * 512;
    const short* bP0 = B0 + (size_t)k * bBatch + (size_t)n0 * 512;
    const short* bP1 = B1 + (size_t)k * bBatch + (size_t)n0 * 512;

    f32x16 acc[4][2];
#pragma unroll
    for (int i = 0; i < 4; i++)
#pragma unroll
        for (int j = 0; j < 2; j++)
            acc[i][j] = (f32x16)(0.f);

    const int srow = tid >> 2;              // 0..127
    const int sc   = tid & 3;               // LDS dest chunk — fixed by lane
    const int khalf = lane >> 5;            // 0..1 : which 8-k group this lane holds
    const int r31   = lane & 31;            // row (A) / col (B) within 32-block

    // one 16KB stage unit: 256 rows x 32 k, one plane; 2 gl_lds16 per thread
#define SROW_STAGE(gsrc, ldst, KK0) do {                                        \
    _Pragma("unroll")                                                           \
    for (int hh = 0; hh < 2; hh++) {                                            \
        int row = hh * 128 + srow;                                              \
        int gq = sc ^ ((row >> 1) & 3);                                         \
        gl_lds16((gsrc) + (size_t)row * 512 + (KK0) + gq * 8,                   \
                 (ldst) + row * 32 + sc * 8);                                   \
    }                                                                           \
} while (0)

// all 8 B-frags: [plane][col-block bj][k-sub kk]
#define READ_B32(BUFC) do {                                                     \
    _Pragma("unroll")                                                           \
    for (int p = 0; p < 2; p++)                                                 \
        _Pragma("unroll")                                                       \
        for (int bj = 0; bj < 2; bj++) {                                        \
            int R = wn + bj * 32 + r31;                                         \
            _Pragma("unroll")                                                   \
            for (int kk = 0; kk < 2; kk++) {                                    \
                int ck = kk * 2 + khalf;                                        \
                int slot = ck ^ ((R >> 1) & 3);                                 \
                bfr[p][bj][kk] = *(const frag_ab*)(ldsB + (BUFC) + p * 8192 + R * 32 + slot * 8); \
            }                                                                   \
        }                                                                       \
} while (0)

// A-frags for one 32-row block: DST[plane][kk]
#define READ_A32(DST, BLK, BUFC) do {                                           \
    int R = wm + (BLK) * 32 + r31;                                              \
    _Pragma("unroll")                                                           \
    for (int p = 0; p < 2; p++)                                                 \
        _Pragma("unroll")                                                       \
        for (int kk = 0; kk < 2; kk++) {                                        \
            int ck = kk * 2 + khalf;                                            \
            int slot = ck ^ ((R >> 1) & 3);                                     \
            DST[p][kk] = *(const frag_ab*)(ldsA + (BUFC) + p * 8192 + R * 32 + slot * 8); \
        }                                                                       \
} while (0)

// 12 MFMA: one 32-row block x 2 col-blocks x 2 k-subs x 3 split products
#define MFMA_Q32(BLK, AR) do {                                                  \
    __builtin_amdgcn_s_setprio(1);                                              \
    _Pragma("unroll")                                                           \
    for (int bj = 0; bj < 2; bj++) {                                            \
        f32x16 c = acc[BLK][bj];                                                \
        _Pragma("unroll")                                                       \
        for (int kk = 0; kk < 2; kk++) {                                        \
            c = __builtin_amdgcn_mfma_f32_32x32x16_bf16(AR[0][kk], bfr[0][bj][kk], c, 0, 0, 0); \
            c = __builtin_amdgcn_mfma_f32_32x32x16_bf16(AR[0][kk], bfr[1][bj][kk], c, 0, 0, 0); \
            c = __builtin_amdgcn_mfma_f32_32x32x16_bf16(AR[1][kk], bfr[0][bj][kk], c, 0, 0, 0); \
        }                                                                       \
        acc[BLK][bj] = c;                                                       \
    }                                                                           \
    __builtin_amdgcn_s_setprio(0);                                              \
} while (0)

#define PH_BAR() do {                                                           \
    __builtin_amdgcn_sched_barrier(0);                                          \
    __builtin_amdgcn_s_barrier();                                               \
    __builtin_amdgcn_sched_barrier(0);                                          \
} while (0)

    // prologue: units 0-5 (K0: B0,B1,A0,A1 ; K1: B0,B1), then vmcnt(4) = K0 staged
    SROW_STAGE(bP0, ldsB + 0,            0);
    SROW_STAGE(bP1, ldsB + 8192,         0);
    SROW_STAGE(aP0, ldsA + 0,            0);
    SROW_STAGE(aP1, ldsA + 8192,         0);
    SROW_STAGE(bP0, ldsB + 16384,        32);
    SROW_STAGE(bP1, ldsB + 16384 + 8192, 32);
    asm volatile("s_waitcnt vmcnt(4)" ::: "memory");
    PH_BAR();

    auto kstep = [&](int T, bool s01, bool s23, int vmn) __attribute__((always_inline)) {
        const int bufc = (T & 1) * 16384;        // current buffer
        const int nb1  = ((T + 1) & 1) * 16384;  // next buffer (A stages)
        const int kk1  = (T + 1) * 32;
        const int kk2  = (T + 2) * 32;
        frag_ab bfr[2][2][2];
        frag_ab aC[2][2], aN[2][2];

        // ---- phase 0: read all B + A-blk0 (boundary) + A-blk1 (ahead);
        //      stage A-p0(T+1) ; MFMA blk0 ----
        READ_B32(bufc);
        READ_A32(aC, 0, bufc);
        READ_A32(aN, 1, bufc);
        if (s01) SROW_STAGE(aP0, ldsA + nb1, kk1);
        MFMA_Q32(0, aC);
        PH_BAR();

        // ---- phase 1: read A-blk2 (ahead) ; stage A-p1(T+1) ; MFMA blk1 ----
        READ_A32(aC, 2, bufc);
        if (s01) SROW_STAGE(aP1, ldsA + nb1 + 8192, kk1);
        MFMA_Q32(1, aN);
        PH_BAR();

        // ---- phase 2: read A-blk3 (ahead) ; stage B-p0(T+2) ; MFMA blk2 ----
        READ_A32(aN, 3, bufc);
        if (s23) SROW_STAGE(bP0, ldsB + bufc, kk2);
        MFMA_Q32(2, aC);
        PH_BAR();

        // ---- phase 3: stage B-p1(T+2) ; MFMA blk3 ; boundary vmcnt ----
        if (s23) SROW_STAGE(bP1, ldsB + bufc + 8192, kk2);
        MFMA_Q32(3, aN);
        if (vmn == 4)      asm volatile("s_waitcnt vmcnt(4)" ::: "memory");
        else if (vmn == 0) asm volatile("s_waitcnt vmcnt(0)" ::: "memory");
        PH_BAR();
    };

    for (int t = 0; t < 14; ++t) kstep(t, true, true, 4);
    kstep(14, true, false, 0);   // stages A-planes of K15; drain
    kstep(15, false, false, -1); // compute-only tail

#undef SROW_STAGE
#undef READ_B32
#undef READ_A32
#undef MFMA_Q32
#undef PH_BAR

    // epilogue: C/D layout col=lane&31, row=(reg&3)+8*(reg>>2)+4*(lane>>5)
    const int er0 = (lane >> 5) * 4;
    const int ec  = lane & 31;
    if (mode == 0) {
        float* C = Cf + (size_t)k * cBatch;
        const float* bb = bias + (size_t)k * biasBatch;
#pragma unroll
        for (int blk = 0; blk < 4; blk++) {
            int rowb = m0 + wm + blk * 32 + er0;
#pragma unroll
            for (int bj = 0; bj < 2; bj++) {
                int col = n0 + wn + bj * 32 + ec;
                if (col < Nout) {
                    float b = bb[col];
#pragma unroll
                    for (int rg = 0; rg < 16; rg++) {
                        int row = rowb + (rg & 3) + 8 * (rg >> 2);
                        C[(size_t)row * ldc + col] = acc[blk][bj][rg] + b;
                    }
                }
            }
        }
    } else {
        short* h0 = H0 + (size_t)k * hBatch;
        short* h1 = H1 + (size_t)k * hBatch;
        const float* bb = bias + (size_t)k * biasBatch;
#pragma unroll
        for (int blk = 0; blk < 4; blk++) {
            int rowb = m0 + wm + blk * 32 + er0;
#pragma unroll
            for (int bj = 0; bj < 2; bj++) {
                int col = n0 + wn + bj * 32 + ec;
                float b = bb[col];
#pragma unroll
                for (int rg = 0; rg < 16; rg++) {
                    int row = rowb + (rg & 3) + 8 * (rg >> 2);
                    float v = fmaxf(acc[blk][bj][rg] + b, 0.f);
                    short s0, s1; split2(v, s0, s1);
                    size_t o = (size_t)row * 512 + col;
                    h0[o] = s0; h1[o] = s1;
                }
            }
        }
    }
}

// ---------------- gate + combine: one wave per sample, wave-synchronous ----------------
// (R3's exact gate — best-measured total; gate redesigns R4-R7 all null/worse)
__global__ __launch_bounds__(256) void gate_combine(
    const float* __restrict__ L,
    const int* __restrict__ n_exp,
    float* __restrict__ out_logits,   // [Bc][C] (offset)
    float* __restrict__ out_gates,    // [Bc][K] (offset)
    int Bc)
{
    const int wv = threadIdx.x >> 6;
    const int lane = threadIdx.x & 63;
    const int b = blockIdx.x * 4 + wv;
    const size_t kcs = (size_t)Bc * C_DIM;
    const float* Lb = L + (size_t)b * C_DIM;

    __shared__ float Sm[4][64];
    __shared__ float Zm[4][8];

    float mx[K_EXP], Zs[K_EXP], dd[36];
#pragma unroll
    for (int k = 0; k < K_EXP; k++) { mx[k] = -INFINITY; Zs[k] = 0.f; }
#pragma unroll
    for (int p = 0; p < 36; p++) dd[p] = 0.f;

    for (int c = lane; c < C_DIM; c += 64) {
        float e[K_EXP];
#pragma unroll
        for (int k = 0; k < K_EXP; k++) {
            float l = Lb[(size_t)k * kcs + c];
            mx[k] = fmaxf(mx[k], l);
            e[k] = __expf(l);
            Zs[k] += e[k];
        }
        int idx = 0;
#pragma unroll
        for (int i = 0; i < K_EXP; i++)
#pragma unroll
            for (int j = i; j < K_EXP; j++) {
                dd[idx] = fmaf(e[i], e[j], dd[idx]);
                idx++;
            }
    }

#pragma unroll
    for (int off = 32; off > 0; off >>= 1) {
#pragma unroll
        for (int k = 0; k < K_EXP; k++) {
            mx[k] = fmaxf(mx[k], __shfl_xor(mx[k], off, 64));
            Zs[k] += __shfl_xor(Zs[k], off, 64);
        }
#pragma unroll
        for (int p = 0; p < 36; p++)
            dd[p] += __shfl_xor(dd[p], off, 64);
    }

    if (lane == 0) {
        int idx = 0;
#pragma unroll
        for (int i = 0; i < K_EXP; i++)
#pragma unroll
            for (int j = i; j < K_EXP; j++) {
                Sm[wv][i * 8 + j] = dd[idx];
                Sm[wv][j * 8 + i] = dd[idx];
                idx++;
            }
#pragma unroll
        for (int k = 0; k < K_EXP; k++) Zm[wv][k] = Zs[k];
    }

    const int ti = lane >> 3, tj = lane & 7;
    const float Zi = Zm[wv][ti], Zj = Zm[wv][tj];
    const float dij = Sm[wv][ti * 8 + tj];
    const float dii = Sm[wv][ti * 8 + ti];
    const float djj = Sm[wv][tj * 8 + tj];
    const float ni = sqrtf(dii) / Zi + EPS_N;
    const float nj = sqrtf(djj) / Zj + EPS_N;
    const float cosij = (dij / (Zi * Zj)) / (ni * nj);

    float conf[K_EXP];
#pragma unroll
    for (int k = 0; k < K_EXP; k++) conf[k] = __expf(mx[k]) / Zs[k];

    int i0 = 0; float bcf = conf[0];
#pragma unroll
    for (int k = 1; k < K_EXP; k++)
        if (conf[k] > bcf) { bcf = conf[k]; i0 = k; }
    unsigned sel = 1u << i0;
    const int n = n_exp[b];

    for (int t = 1; t < K_EXP; t++) {
        float v = ((sel >> tj) & 1u) ? cosij : -INFINITY;
        v = fmaxf(v, __shfl_xor(v, 1, 64));
        v = fmaxf(v, __shfl_xor(v, 2, 64));
        v = fmaxf(v, __shfl_xor(v, 4, 64));
        float dist = ((sel >> ti) & 1u) ? -INFINITY : 1.0f - v;
        float bv = dist; int bi = ti;
#pragma unroll
        for (int off = 8; off < 64; off <<= 1) {
            float ov = __shfl_xor(bv, off, 64);
            int oi = __shfl_xor(bi, off, 64);
            if (ov > bv || (ov == bv && oi < bi)) { bv = ov; bi = oi; }
        }
        if (t < n) sel |= 1u << bi;
    }

    float cmax = -INFINITY;
#pragma unroll
    for (int k = 0; k < K_EXP; k++)
        if ((sel >> k) & 1u) cmax = fmaxf(cmax, conf[k]);
    float g[K_EXP], gsum = 0.f;
#pragma unroll
    for (int k = 0; k < K_EXP; k++) {
        g[k] = ((sel >> k) & 1u) ? __expf((conf[k] - cmax) * TEMP_INV) : 0.f;
        gsum += g[k];
    }
    const float ginv = 1.0f / gsum;
#pragma unroll
    for (int k = 0; k < K_EXP; k++) g[k] *= ginv;

    if (lane == 0) {
        float4* og = (float4*)(out_gates + (size_t)b * K_EXP);
        og[0] = make_float4(g[0], g[1], g[2], g[3]);
        og[1] = make_float4(g[4], g[5], g[6], g[7]);
    }

    for (int c = lane; c < C_DIM; c += 64) {
        float o = 0.f;
#pragma unroll
        for (int k = 0; k < K_EXP; k++)
            o = fmaf(g[k], Lb[(size_t)k * kcs + c], o);
        out_logits[(size_t)b * C_DIM + c] = o;
    }
}

// ---------------- launch ----------------
extern "C" void kernel_launch(void* const* d_in, const int* in_sizes, int n_in,
                              void* d_out, int out_size, void* d_ws, size_t ws_size,
                              hipStream_t stream) {
    const float* z     = (const float*)d_in[0];
    const int*   n_exp = (const int*)d_in[1];
    const float* W1    = (const float*)d_in[2];
    const float* b1    = (const float*)d_in[3];
    const float* W2    = (const float*)d_in[4];
    const float* b2    = (const float*)d_in[5];
    float* out_logits = (float*)d_out;
    float* out_gates  = (float*)d_out + (size_t)B_SZ * C_DIM;

    const size_t zP   = (size_t)B_SZ * D_DIM * 2;
    const size_t w1P  = (size_t)K_EXP * D_DIM * D_DIM * 2;
    const size_t w2P  = (size_t)K_EXP * C_PAD * D_DIM * 2;
    const size_t fixedBytes = 2 * (zP + w1P + w2P);   // ~42 MB

    int nch = 1;
    while (nch < 32 && fixedBytes + (size_t)(B_SZ / nch) * 48384 > ws_size) nch *= 2;
    const int Bc = B_SZ / nch;

    char* w = (char*)d_ws;
    short* zp[2];  zp[0]  = (short*)w; zp[1]  = (short*)(w + zP);  w += 2 * zP;
    short* w1t[2]; w1t[0] = (short*)w; w1t[1] = (short*)(w + w1P); w += 2 * w1P;
    short* w2t[2]; w2t[0] = (short*)w; w2t[1] = (short*)(w + w2P); w += 2 * w2P;
    const size_t hP = (size_t)K_EXP * Bc * D_DIM * 2;
    short* hp[2];  hp[0]  = (short*)w; hp[1]  = (short*)(w + hP);  w += 2 * hP;
    float* Lb = (float*)w;

    prep_z <<<dim3((B_SZ * D_DIM) / 256), 256, 0, stream>>>(z, zp[0], zp[1]);
    prep_w1t<<<dim3(16, 16, K_EXP), 256, 0, stream>>>(W1, w1t[0], w1t[1]);
    prep_w2t<<<dim3(16, 32, K_EXP), 256, 0, stream>>>(W2, w2t[0], w2t[1]);

    const int mt = Bc / 256;    // 256-row m-tiles

    for (int ch = 0; ch < nch; ch++) {
        const int off = ch * Bc;
        const long long zoff = (long long)off * D_DIM;

        // GEMM1: [Bc,512] x [512,512] per expert, BN=256 -> nt=2
        gemm_split<<<dim3(8 * mt * 2), 512, 0, stream>>>(
            zp[0] + zoff, zp[1] + zoff, 0LL,
            w1t[0], w1t[1], (long long)D_DIM * D_DIM,
            b1, D_DIM,
            nullptr, 0LL, 0, D_DIM,
            hp[0], hp[1], (long long)Bc * D_DIM,
            mt, 2, 1);

        // GEMM2: [Bc,512] x [512,1024pad] per expert, BN=256 -> nt=4
        gemm_split<<<dim3(8 * mt * 4), 512, 0, stream>>>(
            hp[0], hp[1], (long long)Bc * D_DIM,
            w2t[0], w2t[1], (long long)C_PAD * D_DIM,
            b2, C_DIM,
            Lb, (long long)Bc * C_DIM, C_DIM, C_DIM,
            nullptr, nullptr, 0LL,
            mt, 4, 0);

        gate_combine<<<dim3(Bc / 4), 256, 0, stream>>>(
            Lb, n_exp + off,
            out_logits + (size_t)off * C_DIM,
            out_gates + (size_t)off * K_EXP,
            Bc);
    }
}

// Round 9
// 517.569 us; speedup vs baseline: 1.0046x; 1.0046x over previous
//
#include <hip/hip_runtime.h>
#include <math.h>

#define B_SZ 8192
#define D_DIM 512
#define C_DIM 1000
#define C_PAD 1024
#define K_EXP 8
#define TEMP_INV 5.0f
#define EPS_N 1e-8f

typedef __attribute__((ext_vector_type(8))) short frag_ab;
typedef __attribute__((ext_vector_type(16))) float f32x16;

__device__ __forceinline__ short f2bf(float f) {
    unsigned u = __builtin_bit_cast(unsigned, f);
    unsigned r = (u + 0x7fffu + ((u >> 16) & 1u)) >> 16;
    return (short)r;
}
__device__ __forceinline__ float bf2f(short s) {
    unsigned u = ((unsigned)(unsigned short)s) << 16;
    return __builtin_bit_cast(float, u);
}
// 2-plane split: v ~= s0 + s1, |residual| ~ 2^-18 |v|
__device__ __forceinline__ void split2(float v, short& s0, short& s1) {
    s0 = f2bf(v);
    s1 = f2bf(v - bf2f(s0));
}

// async global->LDS, 16B per lane (LDS dest wave-contiguous: base + lane*16)
__device__ __forceinline__ void gl_lds16(const short* g, short* l) {
    __builtin_amdgcn_global_load_lds(
        (const __attribute__((address_space(1))) unsigned int*)(const void*)g,
        (__attribute__((address_space(3))) unsigned int*)(void*)l,
        16, 0, 0);
}

// Tiled plane layout (all staged operands): offset(row,k) =
//   (row>>4)*8192 + (k>>3)*128 + (row&15)*8 + (k&7)      [shorts, K=512]
// -> a wave's stage read (4 chunks x 16 rows x 16B) is 1KB contiguous, and the
//    LDS copy of a 16-row tile is chunk-major: conflict-free b128 frag reads.
__device__ __forceinline__ size_t tiled_off(int row, int k) {
    return (size_t)(row >> 4) * 8192 + (size_t)(k >> 3) * 128 + (row & 15) * 8 + (k & 7);
}

// ---------------- one-time prep: transpose + 2-way bf16 split (tiled output) ----------------
__global__ __launch_bounds__(256) void prep_z(const float* __restrict__ z,
                                              short* __restrict__ p0, short* __restrict__ p1) {
    int idx = blockIdx.x * 256 + threadIdx.x;
    int b = idx >> 9, d = idx & 511;
    float v = z[idx];
    short a, bb; split2(v, a, bb);
    size_t o = tiled_off(b, d);
    p0[o] = a; p1[o] = bb;
}

// W1 [K][d][e] -> tiled planes over (row=e, k=d)
__global__ __launch_bounds__(256) void prep_w1t(const float* __restrict__ W1,
                                                short* __restrict__ p0, short* __restrict__ p1) {
    __shared__ float t[32][33];
    const int k = blockIdx.z;
    const int d0 = blockIdx.x * 32;
    const int e0 = blockIdx.y * 32;
    const int tx = threadIdx.x & 31, ty = threadIdx.x >> 5;
    const float* src = W1 + ((size_t)k << 18);
#pragma unroll
    for (int r = 0; r < 4; r++) {
        int d = d0 + ty + 8 * r;
        t[ty + 8 * r][tx] = src[(size_t)d * 512 + e0 + tx];
    }
    __syncthreads();
#pragma unroll
    for (int r = 0; r < 4; r++) {
        int e = e0 + ty + 8 * r;
        int d = d0 + tx;
        float v = t[tx][ty + 8 * r];
        short a, b; split2(v, a, b);
        size_t o = ((size_t)k << 18) + tiled_off(e, d);
        p0[o] = a; p1[o] = b;
    }
}

// W2 [K][e][c] -> tiled planes over (row=c_pad, k=e), zero rows c>=1000
__global__ __launch_bounds__(256) void prep_w2t(const float* __restrict__ W2,
                                                short* __restrict__ p0, short* __restrict__ p1) {
    __shared__ float t[32][33];
    const int k = blockIdx.z;
    const int e0 = blockIdx.x * 32;
    const int c0 = blockIdx.y * 32;
    const int tx = threadIdx.x & 31, ty = threadIdx.x >> 5;
    const float* src = W2 + (size_t)k * (D_DIM * C_DIM);
#pragma unroll
    for (int r = 0; r < 4; r++) {
        int e = e0 + ty + 8 * r;
        int c = c0 + tx;
        t[ty + 8 * r][tx] = (c < C_DIM) ? src[(size_t)e * C_DIM + c] : 0.f;
    }
    __syncthreads();
#pragma unroll
    for (int r = 0; r < 4; r++) {
        int c = c0 + ty + 8 * r;
        int e = e0 + tx;
        float v = t[tx][ty + 8 * r];
        short a, b; split2(v, a, b);
        size_t o = (size_t)k * (C_PAD * D_DIM) + tiled_off(c, e);
        p0[o] = a; p1[o] = b;
    }
}

// ---------------- split-bf16 MFMA GEMM: 256x256 block, 32x32x16 MFMA, tiled LDS ----------------
// R9: R8's shape + chunk-major (tiled) layout -> conflict-free b128 fragment
// reads (R8 had 6.3M bank conflicts from row-contiguous LDS; see journal).
// Stage source is the pre-tiled global layout: each wave reads 1KB contiguous,
// LDS dest linear (gl_lds-legal). No XOR swizzle anywhere.
// C/D layout (verified): col=lane&31, row=(reg&3)+8*(reg>>2)+4*(lane>>5).
__global__ __launch_bounds__(512, 2) void gemm_split(
    const short* __restrict__ A0, const short* __restrict__ A1, long long aBatch,
    const short* __restrict__ B0, const short* __restrict__ B1, long long bBatch,
    const float* __restrict__ bias, int biasBatch,
    float* __restrict__ Cf, long long cBatch, int ldc, int Nout,
    short* __restrict__ H0, short* __restrict__ H1, long long hBatch,
    int mt, int nt, int mode)
{
    const int lin = blockIdx.x;
    const int k = lin & 7;                  // expert ↔ XCD affinity
    const int rem = lin >> 3;
    const int gm = (mt >= 2) ? 2 : 1;       // m-window (512-row L2 window)
    const int win = rem / (gm * nt);
    const int local = rem % (gm * nt);
    const int m0 = (win * gm + local / nt) * 256;
    const int n0 = (local % nt) * 256;

    const int tid = threadIdx.x;
    const int lane = tid & 63;
    const int wv = tid >> 6;                // 0..7
    const int wm = (wv & 1) * 128;          // wave tile: 128 rows x 64 cols
    const int wn = (wv >> 1) * 64;

    // A: 2 bufs x 2 planes x 16KB; B same; total 128 KiB
    __shared__ short lds[65536];
    short* ldsA = lds;
    short* ldsB = lds + 32768;

    const short* aP0 = A0 + (size_t)k * aBatch + (size_t)m0 * 512;
    const short* aP1 = A1 + (size_t)k * aBatch + (size_t)m0 * 512;
    const short* bP0 = B0 + (size_t)k * bBatch + (size_t)n0 * 512;
    const short* bP1 = B1 + (size_t)k * bBatch + (size_t)n0 * 512;

    f32x16 acc[4][2];
#pragma unroll
    for (int i = 0; i < 4; i++)
#pragma unroll
        for (int j = 0; j < 2; j++)
            acc[i][j] = (f32x16)(0.f);

    const int khalf = lane >> 5;            // 0..1 : which 8-k group this lane holds
    const int r31   = lane & 31;            // row (A) / col (B) within 32-block
    const int lq    = lane >> 4;            // stage source chunk select
    const int l16   = lane & 15;            // stage source row-within-tile

    // one 16KB stage unit: 16 row-tiles x 4 chunks, one plane; 2 gl_lds16/thread.
    // Source (tiled global): rt*8192 + (c0+lq)*128 + l16*8  -> 1KB contiguous/wave.
    // Dest: unit + rt*512 + lane*8 shorts (wave-contiguous).
#define SROW_STAGE(gsrc, ldst, KK0) do {                                        \
    const int c0_ = (KK0) >> 3;                                                 \
    _Pragma("unroll")                                                           \
    for (int hh = 0; hh < 2; hh++) {                                            \
        int rt = hh * 8 + wv;                                                   \
        gl_lds16((gsrc) + (size_t)rt * 8192 + (size_t)(c0_ + lq) * 128 + l16 * 8, \
                 (ldst) + rt * 512 + lane * 8);                                 \
    }                                                                           \
} while (0)

// all 8 B-frags: [plane][col-block bj][k-sub kk]; conflict-free chunk-major reads
#define READ_B32(BUFC) do {                                                     \
    _Pragma("unroll")                                                           \
    for (int p = 0; p < 2; p++)                                                 \
        _Pragma("unroll")                                                       \
        for (int bj = 0; bj < 2; bj++) {                                        \
            int R = wn + bj * 32 + r31;                                         \
            int rt = R >> 4, rm = R & 15;                                       \
            _Pragma("unroll")                                                   \
            for (int kk = 0; kk < 2; kk++) {                                    \
                int ck = kk * 2 + khalf;                                        \
                bfr[p][bj][kk] = *(const frag_ab*)(ldsB + (BUFC) + p * 8192 + rt * 512 + ck * 128 + rm * 8); \
            }                                                                   \
        }                                                                       \
} while (0)

// A-frags for one 32-row block: DST[plane][kk]
#define READ_A32(DST, BLK, BUFC) do {                                           \
    int R = wm + (BLK) * 32 + r31;                                              \
    int rt = R >> 4, rm = R & 15;                                               \
    _Pragma("unroll")                                                           \
    for (int p = 0; p < 2; p++)                                                 \
        _Pragma("unroll")                                                       \
        for (int kk = 0; kk < 2; kk++) {                                        \
            int ck = kk * 2 + khalf;                                            \
            DST[p][kk] = *(const frag_ab*)(ldsA + (BUFC) + p * 8192 + rt * 512 + ck * 128 + rm * 8); \
        }                                                                       \
} while (0)

// 12 MFMA: one 32-row block x 2 col-blocks x 2 k-subs x 3 split products
#define MFMA_Q32(BLK, AR) do {                                                  \
    __builtin_amdgcn_s_setprio(1);                                              \
    _Pragma("unroll")                                                           \
    for (int bj = 0; bj < 2; bj++) {                                            \
        f32x16 c = acc[BLK][bj];                                                \
        _Pragma("unroll")                                                       \
        for (int kk = 0; kk < 2; kk++) {                                        \
            c = __builtin_amdgcn_mfma_f32_32x32x16_bf16(AR[0][kk], bfr[0][bj][kk], c, 0, 0, 0); \
            c = __builtin_amdgcn_mfma_f32_32x32x16_bf16(AR[0][kk], bfr[1][bj][kk], c, 0, 0, 0); \
            c = __builtin_amdgcn_mfma_f32_32x32x16_bf16(AR[1][kk], bfr[0][bj][kk], c, 0, 0, 0); \
        }                                                                       \
        acc[BLK][bj] = c;                                                       \
    }                                                                           \
    __builtin_amdgcn_s_setprio(0);                                              \
} while (0)

#define PH_BAR() do {                                                           \
    __builtin_amdgcn_sched_barrier(0);                                          \
    __builtin_amdgcn_s_barrier();                                               \
    __builtin_amdgcn_sched_barrier(0);                                          \
} while (0)

    // prologue: units 0-5 (K0: B0,B1,A0,A1 ; K1: B0,B1), then vmcnt(4) = K0 staged
    SROW_STAGE(bP0, ldsB + 0,            0);
    SROW_STAGE(bP1, ldsB + 8192,         0);
    SROW_STAGE(aP0, ldsA + 0,            0);
    SROW_STAGE(aP1, ldsA + 8192,         0);
    SROW_STAGE(bP0, ldsB + 16384,        32);
    SROW_STAGE(bP1, ldsB + 16384 + 8192, 32);
    asm volatile("s_waitcnt vmcnt(4)" ::: "memory");
    PH_BAR();

    auto kstep = [&](int T, bool s01, bool s23, int vmn) __attribute__((always_inline)) {
        const int bufc = (T & 1) * 16384;        // current buffer
        const int nb1  = ((T + 1) & 1) * 16384;  // next buffer (A stages)
        const int kk1  = (T + 1) * 32;
        const int kk2  = (T + 2) * 32;
        frag_ab bfr[2][2][2];
        frag_ab aC[2][2], aN[2][2];

        // ---- phase 0: read all B + A-blk0 (boundary) + A-blk1 (ahead);
        //      stage A-p0(T+1) ; MFMA blk0 ----
        READ_B32(bufc);
        READ_A32(aC, 0, bufc);
        READ_A32(aN, 1, bufc);
        if (s01) SROW_STAGE(aP0, ldsA + nb1, kk1);
        MFMA_Q32(0, aC);
        PH_BAR();

        // ---- phase 1: read A-blk2 (ahead) ; stage A-p1(T+1) ; MFMA blk1 ----
        READ_A32(aC, 2, bufc);
        if (s01) SROW_STAGE(aP1, ldsA + nb1 + 8192, kk1);
        MFMA_Q32(1, aN);
        PH_BAR();

        // ---- phase 2: read A-blk3 (ahead) ; stage B-p0(T+2) ; MFMA blk2 ----
        READ_A32(aN, 3, bufc);
        if (s23) SROW_STAGE(bP0, ldsB + bufc, kk2);
        MFMA_Q32(2, aC);
        PH_BAR();

        // ---- phase 3: stage B-p1(T+2) ; MFMA blk3 ; boundary vmcnt ----
        if (s23) SROW_STAGE(bP1, ldsB + bufc + 8192, kk2);
        MFMA_Q32(3, aN);
        if (vmn == 4)      asm volatile("s_waitcnt vmcnt(4)" ::: "memory");
        else if (vmn == 0) asm volatile("s_waitcnt vmcnt(0)" ::: "memory");
        PH_BAR();
    };

    for (int t = 0; t < 14; ++t) kstep(t, true, true, 4);
    kstep(14, true, false, 0);   // stages A-planes of K15; drain
    kstep(15, false, false, -1); // compute-only tail

#undef SROW_STAGE
#undef READ_B32
#undef READ_A32
#undef MFMA_Q32
#undef PH_BAR

    // epilogue: C/D layout col=lane&31, row=(reg&3)+8*(reg>>2)+4*(lane>>5)
    const int er0 = (lane >> 5) * 4;
    const int ec  = lane & 31;
    if (mode == 0) {
        float* C = Cf + (size_t)k * cBatch;
        const float* bb = bias + (size_t)k * biasBatch;
#pragma unroll
        for (int blk = 0; blk < 4; blk++) {
            int rowb = m0 + wm + blk * 32 + er0;
#pragma unroll
            for (int bj = 0; bj < 2; bj++) {
                int col = n0 + wn + bj * 32 + ec;
                if (col < Nout) {
                    float b = bb[col];
#pragma unroll
                    for (int rg = 0; rg < 16; rg++) {
                        int row = rowb + (rg & 3) + 8 * (rg >> 2);
                        C[(size_t)row * ldc + col] = acc[blk][bj][rg] + b;
                    }
                }
            }
        }
    } else {
        // H output in tiled layout (consumed by GEMM2's stage)
        short* h0 = H0 + (size_t)k * hBatch;
        short* h1 = H1 + (size_t)k * hBatch;
        const float* bb = bias + (size_t)k * biasBatch;
#pragma unroll
        for (int blk = 0; blk < 4; blk++) {
            int rowb = m0 + wm + blk * 32 + er0;
#pragma unroll
            for (int bj = 0; bj < 2; bj++) {
                int col = n0 + wn + bj * 32 + ec;
                float b = bb[col];
#pragma unroll
                for (int rg = 0; rg < 16; rg++) {
                    int row = rowb + (rg & 3) + 8 * (rg >> 2);
                    float v = fmaxf(acc[blk][bj][rg] + b, 0.f);
                    short s0, s1; split2(v, s0, s1);
                    size_t o = tiled_off(row, col);
                    h0[o] = s0; h1[o] = s1;
                }
            }
        }
    }
}

// ---------------- gate + combine: one wave per sample, wave-synchronous ----------------
// (R3's exact gate — best-measured total; gate redesigns R4-R7 all null/worse)
__global__ __launch_bounds__(256) void gate_combine(
    const float* __restrict__ L,
    const int* __restrict__ n_exp,
    float* __restrict__ out_logits,   // [Bc][C] (offset)
    float* __restrict__ out_gates,    // [Bc][K] (offset)
    int Bc)
{
    const int wv = threadIdx.x >> 6;
    const int lane = threadIdx.x & 63;
    const int b = blockIdx.x * 4 + wv;
    const size_t kcs = (size_t)Bc * C_DIM;
    const float* Lb = L + (size_t)b * C_DIM;

    __shared__ float Sm[4][64];
    __shared__ float Zm[4][8];

    float mx[K_EXP], Zs[K_EXP], dd[36];
#pragma unroll
    for (int k = 0; k < K_EXP; k++) { mx[k] = -INFINITY; Zs[k] = 0.f; }
#pragma unroll
    for (int p = 0; p < 36; p++) dd[p] = 0.f;

    for (int c = lane; c < C_DIM; c += 64) {
        float e[K_EXP];
#pragma unroll
        for (int k = 0; k < K_EXP; k++) {
            float l = Lb[(size_t)k * kcs + c];
            mx[k] = fmaxf(mx[k], l);
            e[k] = __expf(l);
            Zs[k] += e[k];
        }
        int idx = 0;
#pragma unroll
        for (int i = 0; i < K_EXP; i++)
#pragma unroll
            for (int j = i; j < K_EXP; j++) {
                dd[idx] = fmaf(e[i], e[j], dd[idx]);
                idx++;
            }
    }

#pragma unroll
    for (int off = 32; off > 0; off >>= 1) {
#pragma unroll
        for (int k = 0; k < K_EXP; k++) {
            mx[k] = fmaxf(mx[k], __shfl_xor(mx[k], off, 64));
            Zs[k] += __shfl_xor(Zs[k], off, 64);
        }
#pragma unroll
        for (int p = 0; p < 36; p++)
            dd[p] += __shfl_xor(dd[p], off, 64);
    }

    if (lane == 0) {
        int idx = 0;
#pragma unroll
        for (int i = 0; i < K_EXP; i++)
#pragma unroll
            for (int j = i; j < K_EXP; j++) {
                Sm[wv][i * 8 + j] = dd[idx];
                Sm[wv][j * 8 + i] = dd[idx];
                idx++;
            }
#pragma unroll
        for (int k = 0; k < K_EXP; k++) Zm[wv][k] = Zs[k];
    }

    const int ti = lane >> 3, tj = lane & 7;
    const float Zi = Zm[wv][ti], Zj = Zm[wv][tj];
    const float dij = Sm[wv][ti * 8 + tj];
    const float dii = Sm[wv][ti * 8 + ti];
    const float djj = Sm[wv][tj * 8 + tj];
    const float ni = sqrtf(dii) / Zi + EPS_N;
    const float nj = sqrtf(djj) / Zj + EPS_N;
    const float cosij = (dij / (Zi * Zj)) / (ni * nj);

    float conf[K_EXP];
#pragma unroll
    for (int k = 0; k < K_EXP; k++) conf[k] = __expf(mx[k]) / Zs[k];

    int i0 = 0; float bcf = conf[0];
#pragma unroll
    for (int k = 1; k < K_EXP; k++)
        if (conf[k] > bcf) { bcf = conf[k]; i0 = k; }
    unsigned sel = 1u << i0;
    const int n = n_exp[b];

    for (int t = 1; t < K_EXP; t++) {
        float v = ((sel >> tj) & 1u) ? cosij : -INFINITY;
        v = fmaxf(v, __shfl_xor(v, 1, 64));
        v = fmaxf(v, __shfl_xor(v, 2, 64));
        v = fmaxf(v, __shfl_xor(v, 4, 64));
        float dist = ((sel >> ti) & 1u) ? -INFINITY : 1.0f - v;
        float bv = dist; int bi = ti;
#pragma unroll
        for (int off = 8; off < 64; off <<= 1) {
            float ov = __shfl_xor(bv, off, 64);
            int oi = __shfl_xor(bi, off, 64);
            if (ov > bv || (ov == bv && oi < bi)) { bv = ov; bi = oi; }
        }
        if (t < n) sel |= 1u << bi;
    }

    float cmax = -INFINITY;
#pragma unroll
    for (int k = 0; k < K_EXP; k++)
        if ((sel >> k) & 1u) cmax = fmaxf(cmax, conf[k]);
    float g[K_EXP], gsum = 0.f;
#pragma unroll
    for (int k = 0; k < K_EXP; k++) {
        g[k] = ((sel >> k) & 1u) ? __expf((conf[k] - cmax) * TEMP_INV) : 0.f;
        gsum += g[k];
    }
    const float ginv = 1.0f / gsum;
#pragma unroll
    for (int k = 0; k < K_EXP; k++) g[k] *= ginv;

    if (lane == 0) {
        float4* og = (float4*)(out_gates + (size_t)b * K_EXP);
        og[0] = make_float4(g[0], g[1], g[2], g[3]);
        og[1] = make_float4(g[4], g[5], g[6], g[7]);
    }

    for (int c = lane; c < C_DIM; c += 64) {
        float o = 0.f;
#pragma unroll
        for (int k = 0; k < K_EXP; k++)
            o = fmaf(g[k], Lb[(size_t)k * kcs + c], o);
        out_logits[(size_t)b * C_DIM + c] = o;
    }
}

// ---------------- launch ----------------
extern "C" void kernel_launch(void* const* d_in, const int* in_sizes, int n_in,
                              void* d_out, int out_size, void* d_ws, size_t ws_size,
                              hipStream_t stream) {
    const float* z     = (const float*)d_in[0];
    const int*   n_exp = (const int*)d_in[1];
    const float* W1    = (const float*)d_in[2];
    const float* b1    = (const float*)d_in[3];
    const float* W2    = (const float*)d_in[4];
    const float* b2    = (const float*)d_in[5];
    float* out_logits = (float*)d_out;
    float* out_gates  = (float*)d_out + (size_t)B_SZ * C_DIM;

    const size_t zP   = (size_t)B_SZ * D_DIM * 2;
    const size_t w1P  = (size_t)K_EXP * D_DIM * D_DIM * 2;
    const size_t w2P  = (size_t)K_EXP * C_PAD * D_DIM * 2;
    const size_t fixedBytes = 2 * (zP + w1P + w2P);   // ~42 MB

    int nch = 1;
    while (nch < 32 && fixedBytes + (size_t)(B_SZ / nch) * 48384 > ws_size) nch *= 2;
    const int Bc = B_SZ / nch;

    char* w = (char*)d_ws;
    short* zp[2];  zp[0]  = (short*)w; zp[1]  = (short*)(w + zP);  w += 2 * zP;
    short* w1t[2]; w1t[0] = (short*)w; w1t[1] = (short*)(w + w1P); w += 2 * w1P;
    short* w2t[2]; w2t[0] = (short*)w; w2t[1] = (short*)(w + w2P); w += 2 * w2P;
    const size_t hP = (size_t)K_EXP * Bc * D_DIM * 2;
    short* hp[2];  hp[0]  = (short*)w; hp[1]  = (short*)(w + hP);  w += 2 * hP;
    float* Lb = (float*)w;

    prep_z <<<dim3((B_SZ * D_DIM) / 256), 256, 0, stream>>>(z, zp[0], zp[1]);
    prep_w1t<<<dim3(16, 16, K_EXP), 256, 0, stream>>>(W1, w1t[0], w1t[1]);
    prep_w2t<<<dim3(16, 32, K_EXP), 256, 0, stream>>>(W2, w2t[0], w2t[1]);

    const int mt = Bc / 256;    // 256-row m-tiles

    for (int ch = 0; ch < nch; ch++) {
        const int off = ch * Bc;
        const long long zoff = (long long)off * D_DIM;   // off%16==0 -> tile-aligned

        // GEMM1: [Bc,512] x [512,512] per expert, BN=256 -> nt=2
        gemm_split<<<dim3(8 * mt * 2), 512, 0, stream>>>(
            zp[0] + zoff, zp[1] + zoff, 0LL,
            w1t[0], w1t[1], (long long)D_DIM * D_DIM,
            b1, D_DIM,
            nullptr, 0LL, 0, D_DIM,
            hp[0], hp[1], (long long)Bc * D_DIM,
            mt, 2, 1);

        // GEMM2: [Bc,512] x [512,1024pad] per expert, BN=256 -> nt=4
        gemm_split<<<dim3(8 * mt * 4), 512, 0, stream>>>(
            hp[0], hp[1], (long long)Bc * D_DIM,
            w2t[0], w2t[1], (long long)C_PAD * D_DIM,
            b2, C_DIM,
            Lb, (long long)Bc * C_DIM, C_DIM, C_DIM,
            nullptr, nullptr, 0LL,
            mt, 4, 0);

        gate_combine<<<dim3(Bc / 4), 256, 0, stream>>>(
            Lb, n_exp + off,
            out_logits + (size_t)off * C_DIM,
            out_gates + (size_t)off * K_EXP,
            Bc);
    }
}

// Round 10
// 481.897 us; speedup vs baseline: 1.0789x; 1.0740x over previous
//
#include <hip/hip_runtime.h>
#include <math.h>

#define B_SZ 8192
#define D_DIM 512
#define C_DIM 1000
#define C_PAD 1024
#define K_EXP 8
#define TEMP_INV 5.0f
#define EPS_N 1e-8f

typedef __attribute__((ext_vector_type(8))) short frag_ab;
typedef __attribute__((ext_vector_type(4))) float frag_cd;

__device__ __forceinline__ short f2bf(float f) {
    unsigned u = __builtin_bit_cast(unsigned, f);
    unsigned r = (u + 0x7fffu + ((u >> 16) & 1u)) >> 16;
    return (short)r;
}
__device__ __forceinline__ float bf2f(short s) {
    unsigned u = ((unsigned)(unsigned short)s) << 16;
    return __builtin_bit_cast(float, u);
}
// 2-plane split: v ~= s0 + s1, |residual| ~ 2^-18 |v|
__device__ __forceinline__ void split2(float v, short& s0, short& s1) {
    s0 = f2bf(v);
    s1 = f2bf(v - bf2f(s0));
}

// async global->LDS, 16B per lane (LDS dest wave-contiguous: base + lane*16)
__device__ __forceinline__ void gl_lds16(const short* g, short* l) {
    __builtin_amdgcn_global_load_lds(
        (const __attribute__((address_space(1))) unsigned int*)(const void*)g,
        (__attribute__((address_space(3))) unsigned int*)(void*)l,
        16, 0, 0);
}

// ---------------- one-time prep: transpose + 2-way bf16 split ----------------
__global__ __launch_bounds__(256) void prep_z(const float* __restrict__ z,
                                              short* __restrict__ p0, short* __restrict__ p1) {
    int idx = blockIdx.x * 256 + threadIdx.x;
    float v = z[idx];
    short a, b; split2(v, a, b);
    p0[idx] = a; p1[idx] = b;
}

// W1 [K][d][e] -> planes [K][e][d], LDS 32x32 tile transpose
__global__ __launch_bounds__(256) void prep_w1t(const float* __restrict__ W1,
                                                short* __restrict__ p0, short* __restrict__ p1) {
    __shared__ float t[32][33];
    const int k = blockIdx.z;
    const int d0 = blockIdx.x * 32;
    const int e0 = blockIdx.y * 32;
    const int tx = threadIdx.x & 31, ty = threadIdx.x >> 5;
    const float* src = W1 + ((size_t)k << 18);
#pragma unroll
    for (int r = 0; r < 4; r++) {
        int d = d0 + ty + 8 * r;
        t[ty + 8 * r][tx] = src[(size_t)d * 512 + e0 + tx];
    }
    __syncthreads();
#pragma unroll
    for (int r = 0; r < 4; r++) {
        int e = e0 + ty + 8 * r;
        int d = d0 + tx;
        float v = t[tx][ty + 8 * r];
        short a, b; split2(v, a, b);
        size_t o = ((size_t)k << 18) + (size_t)e * 512 + d;
        p0[o] = a; p1[o] = b;
    }
}

// W2 [K][e][c] -> planes [K][c_pad][e] (zero rows c>=1000), 32x32 tile transpose
__global__ __launch_bounds__(256) void prep_w2t(const float* __restrict__ W2,
                                                short* __restrict__ p0, short* __restrict__ p1) {
    __shared__ float t[32][33];
    const int k = blockIdx.z;
    const int e0 = blockIdx.x * 32;
    const int c0 = blockIdx.y * 32;
    const int tx = threadIdx.x & 31, ty = threadIdx.x >> 5;
    const float* src = W2 + (size_t)k * (D_DIM * C_DIM);
#pragma unroll
    for (int r = 0; r < 4; r++) {
        int e = e0 + ty + 8 * r;
        int c = c0 + tx;
        t[ty + 8 * r][tx] = (c < C_DIM) ? src[(size_t)e * C_DIM + c] : 0.f;
    }
    __syncthreads();
#pragma unroll
    for (int r = 0; r < 4; r++) {
        int c = c0 + ty + 8 * r;
        int e = e0 + tx;
        float v = t[tx][ty + 8 * r];
        short a, b; split2(v, a, b);
        size_t o = (size_t)k * (C_PAD * D_DIM) + (size_t)c * 512 + e;
        p0[o] = a; p1[o] = b;
    }
}

// ---------------- split-bf16 MFMA GEMM: 256x256 block, read-ahead 4-phase ----------------
// Best-measured configuration (session ledger: schedule x4, gate x4, shape x2 —
// all alternatives null or worse). 16x16x32 MFMA, chunk-XOR swizzle (0 conflicts),
// one barrier per phase, counted vmcnt(4), A-frag reads one phase ahead.
__global__ __launch_bounds__(512, 2) void gemm_split(
    const short* __restrict__ A0, const short* __restrict__ A1, long long aBatch,
    const short* __restrict__ B0, const short* __restrict__ B1, long long bBatch,
    const float* __restrict__ bias, int biasBatch,
    float* __restrict__ Cf, long long cBatch, int ldc, int Nout,
    short* __restrict__ H0, short* __restrict__ H1, long long hBatch,
    int mt, int nt, int mode)
{
    const int lin = blockIdx.x;
    const int k = lin & 7;                  // expert ↔ XCD affinity
    const int rem = lin >> 3;
    const int gm = (mt >= 2) ? 2 : 1;       // m-window (512-row L2 window)
    const int win = rem / (gm * nt);
    const int local = rem % (gm * nt);
    const int m0 = (win * gm + local / nt) * 256;
    const int n0 = (local % nt) * 256;

    const int tid = threadIdx.x;
    const int lane = tid & 63;
    const int wv = tid >> 6;                // 0..7
    const int wm = (wv & 1) * 128;          // wave tile: 128 rows x 64 cols
    const int wn = (wv >> 1) * 64;

    // A: 2 bufs x 2 planes x 256x32 = 32768 shorts; B same; total 128 KiB
    __shared__ short lds[65536];
    short* ldsA = lds;
    short* ldsB = lds + 32768;

    const short* aP0 = A0 + (size_t)k * aBatch + (size_t)m0 * 512;
    const short* aP1 = A1 + (size_t)k * aBatch + (size_t)m0 * 512;
    const short* bP0 = B0 + (size_t)k * bBatch + (size_t)n0 * 512;
    const short* bP1 = B1 + (size_t)k * bBatch + (size_t)n0 * 512;

    frag_cd acc[8][4];
#pragma unroll
    for (int i = 0; i < 8; i++)
#pragma unroll
        for (int j = 0; j < 4; j++)
            acc[i][j] = (frag_cd){0.f, 0.f, 0.f, 0.f};

    const int srow = tid >> 2;              // 0..127
    const int sc   = tid & 3;               // LDS dest chunk — fixed by lane
    const int q    = lane >> 4;             // desired global k-chunk
    const int rb   = lane & 15;

    // one 16KB stage unit: 256 rows x 32 k, one plane; 2 gl_lds16 per thread
#define SROW_STAGE(gsrc, ldst, KK0) do {                                        \
    _Pragma("unroll")                                                           \
    for (int hh = 0; hh < 2; hh++) {                                            \
        int row = hh * 128 + srow;                                              \
        int gq = sc ^ ((row >> 1) & 3);                                         \
        gl_lds16((gsrc) + (size_t)row * 512 + (KK0) + gq * 8,                   \
                 (ldst) + row * 32 + sc * 8);                                   \
    }                                                                           \
} while (0)

#define READ_B(BUFC) do {                                                       \
    _Pragma("unroll")                                                           \
    for (int j = 0; j < 4; j++) {                                               \
        int R = wn + j * 16 + rb;                                               \
        int slot = q ^ ((R >> 1) & 3);                                          \
        bfr0[j] = *(const frag_ab*)(ldsB + (BUFC) + R * 32 + slot * 8);         \
        bfr1[j] = *(const frag_ab*)(ldsB + (BUFC) + 8192 + R * 32 + slot * 8);  \
    }                                                                           \
} while (0)

#define READ_A(DST, P, BUFC) do {                                               \
    _Pragma("unroll")                                                           \
    for (int ii = 0; ii < 2; ii++) {                                            \
        int R = wm + ((P) * 2 + ii) * 16 + rb;                                  \
        int slot = q ^ ((R >> 1) & 3);                                          \
        DST[ii][0] = *(const frag_ab*)(ldsA + (BUFC) + R * 32 + slot * 8);      \
        DST[ii][1] = *(const frag_ab*)(ldsA + (BUFC) + 8192 + R * 32 + slot * 8);\
    }                                                                           \
} while (0)

#define MFMA_Q(P, AR) do {                                                      \
    __builtin_amdgcn_s_setprio(1);                                              \
    _Pragma("unroll")                                                           \
    for (int ii = 0; ii < 2; ii++)                                              \
        _Pragma("unroll")                                                       \
        for (int j = 0; j < 4; j++) {                                           \
            frag_cd c = acc[(P) * 2 + ii][j];                                   \
            c = __builtin_amdgcn_mfma_f32_16x16x32_bf16(AR[ii][0], bfr0[j], c, 0, 0, 0); \
            c = __builtin_amdgcn_mfma_f32_16x16x32_bf16(AR[ii][0], bfr1[j], c, 0, 0, 0); \
            c = __builtin_amdgcn_mfma_f32_16x16x32_bf16(AR[ii][1], bfr0[j], c, 0, 0, 0); \
            acc[(P) * 2 + ii][j] = c;                                           \
        }                                                                       \
    __builtin_amdgcn_s_setprio(0);                                              \
} while (0)

#define PH_BAR() do {                                                           \
    __builtin_amdgcn_sched_barrier(0);                                          \
    __builtin_amdgcn_s_barrier();                                               \
    __builtin_amdgcn_sched_barrier(0);                                          \
} while (0)

    // prologue: units 0-5 (K0: B0,B1,A0,A1 ; K1: B0,B1), then vmcnt(4) = K0 staged
    SROW_STAGE(bP0, ldsB + 0,            0);
    SROW_STAGE(bP1, ldsB + 8192,         0);
    SROW_STAGE(aP0, ldsA + 0,            0);
    SROW_STAGE(aP1, ldsA + 8192,         0);
    SROW_STAGE(bP0, ldsB + 16384,        32);
    SROW_STAGE(bP1, ldsB + 16384 + 8192, 32);
    asm volatile("s_waitcnt vmcnt(4)" ::: "memory");
    PH_BAR();

    auto kstep = [&](int T, bool s01, bool s23, int vmn) __attribute__((always_inline)) {
        const int bufc = (T & 1) * 16384;        // current buffer
        const int nb1  = ((T + 1) & 1) * 16384;  // next buffer (A stages)
        const int kk1  = (T + 1) * 32;
        const int kk2  = (T + 2) * 32;
        frag_ab bfr0[4], bfr1[4];
        frag_ab aC[2][2], aN[2][2];

        // ---- phase 0: read B + A0 (boundary, same-phase) + A1 (ahead);
        //      stage A-p0(T+1) -> nb1 ; MFMA quad 0 ----
        READ_B(bufc);
        READ_A(aC, 0, bufc);
        READ_A(aN, 1, bufc);
        if (s01) SROW_STAGE(aP0, ldsA + nb1, kk1);
        MFMA_Q(0, aC);
        PH_BAR();

        // ---- phase 1: read A2 (ahead) ; stage A-p1(T+1) ; MFMA quad 1 ----
        READ_A(aC, 2, bufc);
        if (s01) SROW_STAGE(aP1, ldsA + nb1 + 8192, kk1);
        MFMA_Q(1, aN);
        PH_BAR();

        // ---- phase 2: read A3 (ahead) ; stage B-p0(T+2) -> bufc ; MFMA quad 2 ----
        READ_A(aN, 3, bufc);
        if (s23) SROW_STAGE(bP0, ldsB + bufc, kk2);
        MFMA_Q(2, aC);
        PH_BAR();

        // ---- phase 3: stage B-p1(T+2) ; MFMA quad 3 ; boundary vmcnt ----
        if (s23) SROW_STAGE(bP1, ldsB + bufc + 8192, kk2);
        MFMA_Q(3, aN);
        if (vmn == 4)      asm volatile("s_waitcnt vmcnt(4)" ::: "memory");
        else if (vmn == 0) asm volatile("s_waitcnt vmcnt(0)" ::: "memory");
        PH_BAR();
    };

    for (int t = 0; t < 14; ++t) kstep(t, true, true, 4);
    kstep(14, true, false, 0);   // stages A-planes of K15; drain
    kstep(15, false, false, -1); // compute-only tail

#undef SROW_STAGE
#undef READ_B
#undef READ_A
#undef MFMA_Q
#undef PH_BAR

    // epilogue: C/D layout col=lane&15, row=(lane>>4)*4+reg
    const int r0 = (lane >> 4) * 4;
    const int cc = lane & 15;
    if (mode == 0) {
        float* C = Cf + (size_t)k * cBatch;
        const float* bb = bias + (size_t)k * biasBatch;
#pragma unroll
        for (int i = 0; i < 8; i++) {
            int rowb = m0 + wm + i * 16 + r0;
#pragma unroll
            for (int j = 0; j < 4; j++) {
                int col = n0 + wn + j * 16 + cc;
                if (col < Nout) {
                    float b = bb[col];
#pragma unroll
                    for (int r = 0; r < 4; r++)
                        C[(size_t)(rowb + r) * ldc + col] = acc[i][j][r] + b;
                }
            }
        }
    } else {
        short* h0 = H0 + (size_t)k * hBatch;
        short* h1 = H1 + (size_t)k * hBatch;
        const float* bb = bias + (size_t)k * biasBatch;
#pragma unroll
        for (int i = 0; i < 8; i++) {
            int rowb = m0 + wm + i * 16 + r0;
#pragma unroll
            for (int j = 0; j < 4; j++) {
                int col = n0 + wn + j * 16 + cc;
                float b = bb[col];
#pragma unroll
                for (int r = 0; r < 4; r++) {
                    float v = fmaxf(acc[i][j][r] + b, 0.f);
                    short s0, s1; split2(v, s0, s1);
                    size_t o = (size_t)(rowb + r) * 512 + col;
                    h0[o] = s0; h1[o] = s1;
                }
            }
        }
    }
}

// ---------------- gate + combine: one wave per sample, wave-synchronous ----------------
// Best-measured gate (R4-R7 redesigns: split/block-per-sample/float4/async-LDS all
// null or worse; this fused wave-per-sample form ties best total).
__global__ __launch_bounds__(256) void gate_combine(
    const float* __restrict__ L,
    const int* __restrict__ n_exp,
    float* __restrict__ out_logits,   // [Bc][C] (offset)
    float* __restrict__ out_gates,    // [Bc][K] (offset)
    int Bc)
{
    const int wv = threadIdx.x >> 6;
    const int lane = threadIdx.x & 63;
    const int b = blockIdx.x * 4 + wv;
    const size_t kcs = (size_t)Bc * C_DIM;
    const float* Lb = L + (size_t)b * C_DIM;

    __shared__ float Sm[4][64];
    __shared__ float Zm[4][8];

    float mx[K_EXP], Zs[K_EXP], dd[36];
#pragma unroll
    for (int k = 0; k < K_EXP; k++) { mx[k] = -INFINITY; Zs[k] = 0.f; }
#pragma unroll
    for (int p = 0; p < 36; p++) dd[p] = 0.f;

    for (int c = lane; c < C_DIM; c += 64) {
        float e[K_EXP];
#pragma unroll
        for (int k = 0; k < K_EXP; k++) {
            float l = Lb[(size_t)k * kcs + c];
            mx[k] = fmaxf(mx[k], l);
            e[k] = __expf(l);
            Zs[k] += e[k];
        }
        int idx = 0;
#pragma unroll
        for (int i = 0; i < K_EXP; i++)
#pragma unroll
            for (int j = i; j < K_EXP; j++) {
                dd[idx] = fmaf(e[i], e[j], dd[idx]);
                idx++;
            }
    }

#pragma unroll
    for (int off = 32; off > 0; off >>= 1) {
#pragma unroll
        for (int k = 0; k < K_EXP; k++) {
            mx[k] = fmaxf(mx[k], __shfl_xor(mx[k], off, 64));
            Zs[k] += __shfl_xor(Zs[k], off, 64);
        }
#pragma unroll
        for (int p = 0; p < 36; p++)
            dd[p] += __shfl_xor(dd[p], off, 64);
    }

    if (lane == 0) {
        int idx = 0;
#pragma unroll
        for (int i = 0; i < K_EXP; i++)
#pragma unroll
            for (int j = i; j < K_EXP; j++) {
                Sm[wv][i * 8 + j] = dd[idx];
                Sm[wv][j * 8 + i] = dd[idx];
                idx++;
            }
#pragma unroll
        for (int k = 0; k < K_EXP; k++) Zm[wv][k] = Zs[k];
    }

    const int ti = lane >> 3, tj = lane & 7;
    const float Zi = Zm[wv][ti], Zj = Zm[wv][tj];
    const float dij = Sm[wv][ti * 8 + tj];
    const float dii = Sm[wv][ti * 8 + ti];
    const float djj = Sm[wv][tj * 8 + tj];
    const float ni = sqrtf(dii) / Zi + EPS_N;
    const float nj = sqrtf(djj) / Zj + EPS_N;
    const float cosij = (dij / (Zi * Zj)) / (ni * nj);

    float conf[K_EXP];
#pragma unroll
    for (int k = 0; k < K_EXP; k++) conf[k] = __expf(mx[k]) / Zs[k];

    int i0 = 0; float bcf = conf[0];
#pragma unroll
    for (int k = 1; k < K_EXP; k++)
        if (conf[k] > bcf) { bcf = conf[k]; i0 = k; }
    unsigned sel = 1u << i0;
    const int n = n_exp[b];

    for (int t = 1; t < K_EXP; t++) {
        float v = ((sel >> tj) & 1u) ? cosij : -INFINITY;
        v = fmaxf(v, __shfl_xor(v, 1, 64));
        v = fmaxf(v, __shfl_xor(v, 2, 64));
        v = fmaxf(v, __shfl_xor(v, 4, 64));
        float dist = ((sel >> ti) & 1u) ? -INFINITY : 1.0f - v;
        float bv = dist; int bi = ti;
#pragma unroll
        for (int off = 8; off < 64; off <<= 1) {
            float ov = __shfl_xor(bv, off, 64);
            int oi = __shfl_xor(bi, off, 64);
            if (ov > bv || (ov == bv && oi < bi)) { bv = ov; bi = oi; }
        }
        if (t < n) sel |= 1u << bi;
    }

    float cmax = -INFINITY;
#pragma unroll
    for (int k = 0; k < K_EXP; k++)
        if ((sel >> k) & 1u) cmax = fmaxf(cmax, conf[k]);
    float g[K_EXP], gsum = 0.f;
#pragma unroll
    for (int k = 0; k < K_EXP; k++) {
        g[k] = ((sel >> k) & 1u) ? __expf((conf[k] - cmax) * TEMP_INV) : 0.f;
        gsum += g[k];
    }
    const float ginv = 1.0f / gsum;
#pragma unroll
    for (int k = 0; k < K_EXP; k++) g[k] *= ginv;

    if (lane == 0) {
        float4* og = (float4*)(out_gates + (size_t)b * K_EXP);
        og[0] = make_float4(g[0], g[1], g[2], g[3]);
        og[1] = make_float4(g[4], g[5], g[6], g[7]);
    }

    for (int c = lane; c < C_DIM; c += 64) {
        float o = 0.f;
#pragma unroll
        for (int k = 0; k < K_EXP; k++)
            o = fmaf(g[k], Lb[(size_t)k * kcs + c], o);
        out_logits[(size_t)b * C_DIM + c] = o;
    }
}

// ---------------- launch ----------------
extern "C" void kernel_launch(void* const* d_in, const int* in_sizes, int n_in,
                              void* d_out, int out_size, void* d_ws, size_t ws_size,
                              hipStream_t stream) {
    const float* z     = (const float*)d_in[0];
    const int*   n_exp = (const int*)d_in[1];
    const float* W1    = (const float*)d_in[2];
    const float* b1    = (const float*)d_in[3];
    const float* W2    = (const float*)d_in[4];
    const float* b2    = (const float*)d_in[5];
    float* out_logits = (float*)d_out;
    float* out_gates  = (float*)d_out + (size_t)B_SZ * C_DIM;

    const size_t zP   = (size_t)B_SZ * D_DIM * 2;
    const size_t w1P  = (size_t)K_EXP * D_DIM * D_DIM * 2;
    const size_t w2P  = (size_t)K_EXP * C_PAD * D_DIM * 2;
    const size_t fixedBytes = 2 * (zP + w1P + w2P);   // ~42 MB

    int nch = 1;
    while (nch < 32 && fixedBytes + (size_t)(B_SZ / nch) * 48384 > ws_size) nch *= 2;
    const int Bc = B_SZ / nch;

    char* w = (char*)d_ws;
    short* zp[2];  zp[0]  = (short*)w; zp[1]  = (short*)(w + zP);  w += 2 * zP;
    short* w1t[2]; w1t[0] = (short*)w; w1t[1] = (short*)(w + w1P); w += 2 * w1P;
    short* w2t[2]; w2t[0] = (short*)w; w2t[1] = (short*)(w + w2P); w += 2 * w2P;
    const size_t hP = (size_t)K_EXP * Bc * D_DIM * 2;
    short* hp[2];  hp[0]  = (short*)w; hp[1]  = (short*)(w + hP);  w += 2 * hP;
    float* Lb = (float*)w;

    prep_z <<<dim3((B_SZ * D_DIM) / 256), 256, 0, stream>>>(z, zp[0], zp[1]);
    prep_w1t<<<dim3(16, 16, K_EXP), 256, 0, stream>>>(W1, w1t[0], w1t[1]);
    prep_w2t<<<dim3(16, 32, K_EXP), 256, 0, stream>>>(W2, w2t[0], w2t[1]);

    const int mt = Bc / 256;    // 256-row m-tiles

    for (int ch = 0; ch < nch; ch++) {
        const int off = ch * Bc;
        const long long zoff = (long long)off * D_DIM;

        // GEMM1: [Bc,512] x [512,512] per expert, BN=256 -> nt=2
        gemm_split<<<dim3(8 * mt * 2), 512, 0, stream>>>(
            zp[0] + zoff, zp[1] + zoff, 0LL,
            w1t[0], w1t[1], (long long)D_DIM * D_DIM,
            b1, D_DIM,
            nullptr, 0LL, 0, D_DIM,
            hp[0], hp[1], (long long)Bc * D_DIM,
            mt, 2, 1);

        // GEMM2: [Bc,512] x [512,1024pad] per expert, BN=256 -> nt=4
        gemm_split<<<dim3(8 * mt * 4), 512, 0, stream>>>(
            hp[0], hp[1], (long long)Bc * D_DIM,
            w2t[0], w2t[1], (long long)C_PAD * D_DIM,
            b2, C_DIM,
            Lb, (long long)Bc * C_DIM, C_DIM, C_DIM,
            nullptr, nullptr, 0LL,
            mt, 4, 0);

        gate_combine<<<dim3(Bc / 4), 256, 0, stream>>>(
            Lb, n_exp + off,
            out_logits + (size_t)off * C_DIM,
            out_gates + (size_t)off * K_EXP,
            Bc);
    }
}